// Round 1
// baseline (188.996 us; speedup 1.0000x reference)
//
#include <hip/hip_runtime.h>
#include <stdint.h>

#define NT 2048
#define DT 128

typedef __bf16 bf16x8 __attribute__((ext_vector_type(8)));
typedef __bf16 bf16x4 __attribute__((ext_vector_type(4)));
typedef float  f32x16 __attribute__((ext_vector_type(16)));

__device__ __forceinline__ void gl_lds16(const void* g, void* l) {
    // async global->LDS, 16B per lane; LDS side is wave-uniform base + lane*16
    __builtin_amdgcn_global_load_lds(
        (__attribute__((address_space(1))) void*)(uintptr_t)g,
        (__attribute__((address_space(3))) void*)(uint32_t)(uintptr_t)l,
        16, 0, 0);
}

// D = A*B + C, 32x32x16 bf16.
// A: lane holds A[m=lane&31][k=(lane>>5)*8+j], j=0..7 (8 bf16 = 4 VGPR)
// B: lane holds B[k=(lane>>5)*8+j][n=lane&31]
// C/D: col=lane&31, row=(reg&3)+8*(reg>>2)+4*(lane>>5)   [verified m74/m101]
__global__ __launch_bounds__(256, 1)
void sig_attn(const float* __restrict__ Q, const float* __restrict__ K,
              const float* __restrict__ V, float* __restrict__ out)
{
    __shared__ __align__(16) unsigned char smem[49152];
    __bf16* Qs  = (__bf16*)smem;              // [n 64][d 128] bf16, xor-swizzled 8-elem blocks
    __bf16* Vs  = (__bf16*)(smem + 16384);    // [v 128][n 64] bf16, swizzled
    __bf16* Ss  = (__bf16*)(smem + 32768);    // [m 128][n 64] bf16, swizzled
    float*  Kst = (float*) (smem + 32768);    // alias of Ss: [32][128] fp32 K staging (pre-loop only)

    const int t   = threadIdx.x;
    const int w   = t >> 6;     // wave 0..3
    const int l   = t & 63;     // lane
    const int lq  = l >> 5;     // half-wave
    const int l31 = l & 31;

    const int bid    = blockIdx.x;
    const int b      = bid & 7;          // XCD-pinned batch
    const int mt     = (bid >> 3) & 15;
    const int ns     = bid >> 7;
    const int m_blk  = mt * 128;
    const int n_base = ns * 1024;

    const float* Qb = Q + (size_t)b * DT * NT;
    const float* Kb = K + (size_t)b * DT * NT;
    const float* Vb = V + (size_t)b * DT * NT;
    float*       Ob = out + (size_t)b * DT * NT;

    const int mh = (w >> 1) * 64;   // this wave's m-half (GEMM1 and GEMM2)
    const int nh = (w & 1) * 32;    // this wave's n-half (GEMM1)
    const int vh = (w & 1) * 64;    // this wave's v-half (GEMM2)

    // ---------------- K tile -> register-resident B fragments ----------------
    // kf[kstep d/16][m-subtile]; covers d=0..127 x m = m_blk+mh .. +64
    bf16x8 kf[8][2];
    #pragma unroll
    for (int c = 0; c < 4; ++c) {
        #pragma unroll
        for (int p = 0; p < 4; ++p) {
            const int i = w * 4 + p;  // 0..15, 2 rows per instruction
            const float* g = Kb + (size_t)(c * 32 + 2 * i + lq) * NT + m_blk + l31 * 4;
            gl_lds16(g, Kst + (size_t)(2 * i) * 128);
        }
        __syncthreads();
        #pragma unroll
        for (int kk = 0; kk < 2; ++kk) {
            #pragma unroll
            for (int tm = 0; tm < 2; ++tm) {
                const int m0 = mh + 32 * tm;
                bf16x8 f;
                #pragma unroll
                for (int j = 0; j < 8; ++j)
                    f[j] = (__bf16)Kst[(kk * 16 + lq * 8 + j) * 128 + m0 + l31];
                kf[2 * c + kk][tm] = f;
            }
        }
        __syncthreads();
    }

    f32x16 oacc[2][2];
    #pragma unroll
    for (int a = 0; a < 2; ++a)
        #pragma unroll
        for (int c2 = 0; c2 < 2; ++c2)
            #pragma unroll
            for (int r = 0; r < 16; ++r)
                oacc[a][c2][r] = 0.0f;

    // ---------------- main loop over n-chunks of 64 ----------------
    for (int it = 0; it < 16; ++it) {
        const int n0 = n_base + it * 64;

        // stage Q -> bf16 [n][d] transposed (each thread: 4 d-values of one n column)
        #pragma unroll
        for (int p = 0; p < 8; ++p) {
            const int dbase = p * 16 + w * 4;
            const float* g = Qb + (size_t)dbase * NT + n0 + l;
            const float f0 = g[0];
            const float f1 = g[NT];
            const float f2 = g[2 * NT];
            const float f3 = g[3 * NT];
            bf16x4 pk;
            pk[0] = (__bf16)f0; pk[1] = (__bf16)f1; pk[2] = (__bf16)f2; pk[3] = (__bf16)f3;
            const int bn  = 2 * p + (w >> 1);
            const int bnp = bn ^ (l & 15);
            *(bf16x4*)&Qs[l * 128 + bnp * 8 + (w & 1) * 4] = pk;
        }
        // stage V -> bf16 [v][n] natural
        #pragma unroll
        for (int p = 0; p < 8; ++p) {
            const int v  = p * 16 + (t >> 4);
            const int ng = t & 15;
            const float4 vv = *(const float4*)(Vb + (size_t)v * NT + n0 + ng * 4);
            bf16x4 pk;
            pk[0] = (__bf16)vv.x; pk[1] = (__bf16)vv.y; pk[2] = (__bf16)vv.z; pk[3] = (__bf16)vv.w;
            const int bn  = ng >> 1;
            const int bnp = bn ^ (v & 7);
            *(bf16x4*)&Vs[v * 64 + bnp * 8 + (ng & 1) * 4] = pk;
        }
        __syncthreads();

        // GEMM1: S[nh..nh+32][mh..mh+64] = Q^T K  (K from registers)
        f32x16 sacc[2];
        #pragma unroll
        for (int tm = 0; tm < 2; ++tm)
            #pragma unroll
            for (int r = 0; r < 16; ++r)
                sacc[tm][r] = 0.0f;

        #pragma unroll
        for (int k = 0; k < 8; ++k) {
            const int nl  = nh + l31;
            const int bn  = 2 * k + lq;
            const int bnp = bn ^ (nl & 15);
            const bf16x8 af = *(const bf16x8*)&Qs[nl * 128 + bnp * 8];
            sacc[0] = __builtin_amdgcn_mfma_f32_32x32x16_bf16(af, kf[k][0], sacc[0], 0, 0, 0);
            sacc[1] = __builtin_amdgcn_mfma_f32_32x32x16_bf16(af, kf[k][1], sacc[1], 0, 0, 0);
        }

        // sigmoid(x/sqrt(128)) -> bf16 -> Ss[m][n]
        #pragma unroll
        for (int tm = 0; tm < 2; ++tm) {
            const int mrow = mh + 32 * tm + l31;
            #pragma unroll
            for (int g4 = 0; g4 < 4; ++g4) {
                bf16x4 pk;
                #pragma unroll
                for (int rr = 0; rr < 4; ++rr) {
                    const float x = sacc[tm][4 * g4 + rr];
                    const float e = __expf(x * -0.08838834764831845f);
                    pk[rr] = (__bf16)__builtin_amdgcn_rcpf(1.0f + e);
                }
                const int nb  = nh + 8 * g4 + 4 * lq;   // n-local base, multiple of 4
                const int bn  = nb >> 3;
                const int bnp = bn ^ (mrow & 7);
                *(bf16x4*)&Ss[mrow * 64 + bnp * 8 + (nb & 7)] = pk;
            }
        }
        __syncthreads();

        // GEMM2: out[vh..vh+64][mh..mh+64] += V * S
        #pragma unroll
        for (int k4 = 0; k4 < 4; ++k4) {
            const int bnb = 2 * k4 + lq;
            bf16x8 av[2], bs[2];
            #pragma unroll
            for (int tv = 0; tv < 2; ++tv) {
                const int vrow = vh + 32 * tv + l31;
                const int bnp  = bnb ^ (vrow & 7);
                av[tv] = *(const bf16x8*)&Vs[vrow * 64 + bnp * 8];
            }
            #pragma unroll
            for (int tm = 0; tm < 2; ++tm) {
                const int mrow = mh + 32 * tm + l31;
                const int bnp  = bnb ^ (mrow & 7);
                bs[tm] = *(const bf16x8*)&Ss[mrow * 64 + bnp * 8];
            }
            #pragma unroll
            for (int tv = 0; tv < 2; ++tv)
                #pragma unroll
                for (int tm = 0; tm < 2; ++tm)
                    oacc[tv][tm] = __builtin_amdgcn_mfma_f32_32x32x16_bf16(
                        av[tv], bs[tm], oacc[tv][tm], 0, 0, 0);
        }
        __syncthreads();
    }

    // ---------------- epilogue: merge n-split partials ----------------
    #pragma unroll
    for (int tv = 0; tv < 2; ++tv) {
        #pragma unroll
        for (int tm = 0; tm < 2; ++tm) {
            #pragma unroll
            for (int r = 0; r < 16; ++r) {
                const int v = vh + 32 * tv + (r & 3) + 8 * (r >> 2) + 4 * lq;
                const int m = m_blk + mh + 32 * tm + l31;
                atomicAdd(&Ob[(size_t)v * NT + m], oacc[tv][tm][r]);
            }
        }
    }
}

extern "C" void kernel_launch(void* const* d_in, const int* in_sizes, int n_in,
                              void* d_out, int out_size, void* d_ws, size_t ws_size,
                              hipStream_t stream) {
    (void)in_sizes; (void)n_in; (void)d_ws; (void)ws_size;
    const float* Q = (const float*)d_in[0];
    const float* K = (const float*)d_in[1];
    const float* V = (const float*)d_in[2];
    float* O = (float*)d_out;
    // harness re-poisons d_out with 0xAA before every launch; atomics need zeros
    hipMemsetAsync(d_out, 0, (size_t)out_size * sizeof(float), stream);
    sig_attn<<<dim3(256), dim3(256), 0, stream>>>(Q, K, V, O);
}

// Round 2
// 128.292 us; speedup vs baseline: 1.4732x; 1.4732x over previous
//
#include <hip/hip_runtime.h>
#include <stdint.h>

#define NT 2048
#define DT 128

typedef __bf16 bf16x8 __attribute__((ext_vector_type(8)));
typedef __bf16 bf16x4 __attribute__((ext_vector_type(4)));
typedef float  f32x16 __attribute__((ext_vector_type(16)));

// mfma_f32_32x32x16_bf16 conventions (verified by round-1 pass):
//  A: lane holds A[row=lane&31][k=(lane>>5)*8+j]
//  B: lane holds B[k=(lane>>5)*8+j][col=lane&31]
//  C/D: col=lane&31, row=(reg&3)+8*(reg>>2)+4*(lane>>5)
__global__ __launch_bounds__(512, 4)
void sig_attn(const float* __restrict__ Q, const float* __restrict__ K,
              const float* __restrict__ V, float* __restrict__ out)
{
    __shared__ __align__(16) __bf16 Qs[64 * 128];   // [n][d], 8-elem blocks xor-swizzled by n&15
    __shared__ __align__(16) __bf16 Vs[128 * 64];   // [v][n], swizzled by v&7
    __shared__ __align__(16) __bf16 Ss[128 * 64];   // [m][n], swizzled by m&7

    const int t   = threadIdx.x;
    const int w   = t >> 6;      // wave 0..7
    const int l   = t & 63;
    const int lq  = l >> 5;
    const int l31 = l & 31;
    const int wm  = w & 3;       // 32-wide m-column
    const int wn  = w >> 2;      // GEMM1 n-half / GEMM2 v-half

    const int bid    = blockIdx.x;
    const int b      = bid & 7;          // XCD-pinned batch
    const int mt     = (bid >> 3) & 15;
    const int ns     = bid >> 7;         // 0..3
    const int m_blk  = mt * 128;
    const int n_base = ns * 512;

    const float* Qb = Q + (size_t)b * DT * NT;
    const float* Kb = K + (size_t)b * DT * NT;
    const float* Vb = V + (size_t)b * DT * NT;
    float*       Ob = out + (size_t)b * DT * NT;

    const int mrow = 32 * wm + l31;      // local m within 128-tile

    // ---- K -> register-resident B-fragments: kf[k] holds K[d=16k+8lq+j][m_blk+mrow]
    bf16x8 kf[8];
    #pragma unroll
    for (int half = 0; half < 2; ++half) {
        float tmp[4][8];
        #pragma unroll
        for (int k2 = 0; k2 < 4; ++k2)
            #pragma unroll
            for (int j = 0; j < 8; ++j)
                tmp[k2][j] = Kb[(size_t)((half * 4 + k2) * 16 + lq * 8 + j) * NT + m_blk + mrow];
        #pragma unroll
        for (int k2 = 0; k2 < 4; ++k2) {
            bf16x8 f;
            #pragma unroll
            for (int j = 0; j < 8; ++j) f[j] = (__bf16)tmp[k2][j];
            kf[half * 4 + k2] = f;
        }
    }

    f32x16 oacc[2];
    #pragma unroll
    for (int tv = 0; tv < 2; ++tv)
        #pragma unroll
        for (int r = 0; r < 16; ++r)
            oacc[tv][r] = 0.0f;

    // ---- software-pipelined Q prefetch (16 fp32/thread, one iter ahead)
    float qp[16];
    #pragma unroll
    for (int p = 0; p < 4; ++p)
        #pragma unroll
        for (int i = 0; i < 4; ++i)
            qp[p * 4 + i] = Qb[(size_t)(p * 32 + 4 * w + i) * NT + n_base + l];

    for (int it = 0; it < 8; ++it) {
        const int n0 = n_base + it * 64;

        // V loads, batched issue (single latency exposure)
        float4 vp[4];
        #pragma unroll
        for (int p = 0; p < 4; ++p)
            vp[p] = *(const float4*)(Vb + (size_t)(p * 32 + (t >> 4)) * NT + n0 + 4 * (t & 15));

        // store prefetched Q -> Qs [n][d] (element d sits at block d>>3 ^ (n&15), offset d&7)
        #pragma unroll
        for (int p = 0; p < 4; ++p) {
            bf16x4 pk;
            pk[0] = (__bf16)qp[p * 4 + 0];
            pk[1] = (__bf16)qp[p * 4 + 1];
            pk[2] = (__bf16)qp[p * 4 + 2];
            pk[3] = (__bf16)qp[p * 4 + 3];
            const int bd  = 4 * p + (w >> 1);
            const int bdp = bd ^ (l & 15);
            *(bf16x4*)&Qs[l * 128 + bdp * 8 + 4 * (w & 1)] = pk;
        }
        // store V -> Vs [v][n] (element n at block n>>3 ^ (v&7), offset n&7)
        #pragma unroll
        for (int p = 0; p < 4; ++p) {
            const int v  = p * 32 + (t >> 4);
            const int ng = t & 15;
            bf16x4 pk;
            pk[0] = (__bf16)vp[p].x;
            pk[1] = (__bf16)vp[p].y;
            pk[2] = (__bf16)vp[p].z;
            pk[3] = (__bf16)vp[p].w;
            const int bnp = (ng >> 1) ^ (v & 7);
            *(bf16x4*)&Vs[v * 64 + bnp * 8 + 4 * (ng & 1)] = pk;
        }
        __syncthreads();

        // GEMM1: sacc = S-tile [n = 32wn+rowmap][m = 32wm+l31]
        f32x16 sacc;
        #pragma unroll
        for (int r = 0; r < 16; ++r) sacc[r] = 0.0f;
        const int nrow = 32 * wn + l31;
        #pragma unroll
        for (int k = 0; k < 8; ++k) {
            const bf16x8 af =
                *(const bf16x8*)&Qs[nrow * 128 + ((2 * k + lq) ^ (nrow & 15)) * 8];
            sacc = __builtin_amdgcn_mfma_f32_32x32x16_bf16(af, kf[k], sacc, 0, 0, 0);
        }

        // sigmoid(x/sqrt(128)) -> Ss [m][n]
        #pragma unroll
        for (int g = 0; g < 4; ++g) {
            bf16x4 pk;
            #pragma unroll
            for (int rr = 0; rr < 4; ++rr) {
                const float x = sacc[4 * g + rr];
                const float e = __expf(x * -0.08838834764831845f);
                pk[rr] = (__bf16)__builtin_amdgcn_rcpf(1.0f + e);
            }
            const int bnp = (4 * wn + g) ^ (mrow & 7);
            *(bf16x4*)&Ss[mrow * 64 + bnp * 8 + 4 * lq] = pk;
        }
        __syncthreads();

        // prefetch next iteration's Q (latency hides behind GEMM2)
        const int n0n = n_base + ((it + 1) & 7) * 64;
        #pragma unroll
        for (int p = 0; p < 4; ++p)
            #pragma unroll
            for (int i = 0; i < 4; ++i)
                qp[p * 4 + i] = Qb[(size_t)(p * 32 + 4 * w + i) * NT + n0n + l];

        // GEMM2: oacc[tv] += V[v-tile] * S[m-col]
        #pragma unroll
        for (int k = 0; k < 4; ++k) {
            const int sw = 2 * k + lq;
            const bf16x8 av0 =
                *(const bf16x8*)&Vs[(64 * wn + l31) * 64 + (sw ^ (l31 & 7)) * 8];
            const bf16x8 av1 =
                *(const bf16x8*)&Vs[(64 * wn + 32 + l31) * 64 + (sw ^ (l31 & 7)) * 8];
            const bf16x8 bs =
                *(const bf16x8*)&Ss[mrow * 64 + (sw ^ (mrow & 7)) * 8];
            oacc[0] = __builtin_amdgcn_mfma_f32_32x32x16_bf16(av0, bs, oacc[0], 0, 0, 0);
            oacc[1] = __builtin_amdgcn_mfma_f32_32x32x16_bf16(av1, bs, oacc[1], 0, 0, 0);
        }
        __syncthreads();
    }

    // ---- epilogue: merge 4 n-split partials via fp32 atomics
    #pragma unroll
    for (int tv = 0; tv < 2; ++tv) {
        #pragma unroll
        for (int r = 0; r < 16; ++r) {
            const int v = 64 * wn + 32 * tv + (r & 3) + 8 * (r >> 2) + 4 * lq;
            const int m = m_blk + mrow;
            atomicAdd(&Ob[(size_t)v * NT + m], oacc[tv][r]);
        }
    }
}

extern "C" void kernel_launch(void* const* d_in, const int* in_sizes, int n_in,
                              void* d_out, int out_size, void* d_ws, size_t ws_size,
                              hipStream_t stream) {
    (void)in_sizes; (void)n_in; (void)d_ws; (void)ws_size;
    const float* Q = (const float*)d_in[0];
    const float* K = (const float*)d_in[1];
    const float* V = (const float*)d_in[2];
    float* O = (float*)d_out;
    // harness re-poisons d_out with 0xAA before every launch; atomics need zeros
    hipMemsetAsync(d_out, 0, (size_t)out_size * sizeof(float), stream);
    sig_attn<<<dim3(512), dim3(512), 0, stream>>>(Q, K, V, O);
}

// Round 3
// 125.904 us; speedup vs baseline: 1.5011x; 1.0190x over previous
//
#include <hip/hip_runtime.h>
#include <stdint.h>

#define NT 2048
#define DT 128

typedef __bf16 bf16x8 __attribute__((ext_vector_type(8)));
typedef __bf16 bf16x4 __attribute__((ext_vector_type(4)));
typedef float  f32x16 __attribute__((ext_vector_type(16)));

// mfma_f32_32x32x16_bf16:
//  A: lane holds A[row=lane&31][k=(lane>>5)*8+j]
//  B: lane holds B[k=(lane>>5)*8+j][col=lane&31]
//  C/D: col=lane&31, row=(reg&3)+8*(reg>>2)+4*(lane>>5)
// WSMODE 0: write per-block partial [128v][128m] to ws + bid*16384 (no atomics)
// WSMODE 1: fallback atomicAdd into out (host memsets out first)
template <int WSMODE>
__global__ __launch_bounds__(512, 4)
void sig_attn(const float* __restrict__ Q, const float* __restrict__ K,
              const float* __restrict__ V, float* __restrict__ outp)
{
    __shared__ __align__(16) __bf16 Qs[64 * 128];     // [n][d], 16B granules xor-swizzled by n&15
    __shared__ __align__(16) __bf16 Ss[128 * 64];     // [m][n], swizzled by m&7
    __shared__ __align__(16) __bf16 Vs[2][128 * 64];  // [v][n] double-buffered, swizzled by v&7

    const int t   = threadIdx.x;
    const int w   = t >> 6;      // wave 0..7
    const int l   = t & 63;
    const int lq  = l >> 5;
    const int l31 = l & 31;
    const int wm  = w & 3;       // 32-wide m-column
    const int wn  = w >> 2;      // GEMM1 n-half / GEMM2 v-half

    const int bid    = blockIdx.x;
    const int b      = bid & 7;          // XCD-pinned batch
    const int mt     = (bid >> 3) & 15;
    const int ns     = bid >> 7;         // 0..3
    const int m_blk  = mt * 128;
    const int n_base = ns * 512;

    const float* Qb = Q + (size_t)b * DT * NT;
    const float* Kb = K + (size_t)b * DT * NT;
    const float* Vb = V + (size_t)b * DT * NT;

    const int mrow = 32 * wm + l31;      // local m within 128-tile

    // ---- K -> register-resident B-fragments: kf[k] holds K[d=16k+8lq+j][m_blk+mrow]
    bf16x8 kf[8];
    #pragma unroll
    for (int half = 0; half < 2; ++half) {
        float tmp[4][8];
        #pragma unroll
        for (int k2 = 0; k2 < 4; ++k2)
            #pragma unroll
            for (int j = 0; j < 8; ++j)
                tmp[k2][j] = Kb[(size_t)((half * 4 + k2) * 16 + lq * 8 + j) * NT + m_blk + mrow];
        #pragma unroll
        for (int k2 = 0; k2 < 4; ++k2) {
            bf16x8 f;
            #pragma unroll
            for (int j = 0; j < 8; ++j) f[j] = (__bf16)tmp[k2][j];
            kf[half * 4 + k2] = f;
        }
    }

    f32x16 oacc[2];
    #pragma unroll
    for (int tv = 0; tv < 2; ++tv)
        #pragma unroll
        for (int r = 0; r < 16; ++r)
            oacc[tv][r] = 0.0f;

    // ---- prefetch iter 0: Q (16 scalars: d-runs of 8) + V (4 float4)
    float qp[16];
    #pragma unroll
    for (int r = 0; r < 2; ++r)
        #pragma unroll
        for (int j = 0; j < 8; ++j)
            qp[r * 8 + j] = Qb[(size_t)(64 * r + 8 * w + j) * NT + n_base + l];
    float4 vp[4];
    #pragma unroll
    for (int p = 0; p < 4; ++p)
        vp[p] = *(const float4*)(Vb + (size_t)(p * 32 + (t >> 4)) * NT + n_base + 4 * (t & 15));

    for (int it = 0; it < 8; ++it) {
        __bf16* Vbuf = Vs[it & 1];

        // ---- store prefetched Q: 2x ds_write_b128, granule (8r+w) ^ (n&15)
        #pragma unroll
        for (int r = 0; r < 2; ++r) {
            bf16x8 pk;
            #pragma unroll
            for (int j = 0; j < 8; ++j) pk[j] = (__bf16)qp[r * 8 + j];
            *(bf16x8*)&Qs[l * 128 + ((8 * r + w) ^ (l & 15)) * 8] = pk;
        }
        // ---- store prefetched V
        #pragma unroll
        for (int p = 0; p < 4; ++p) {
            const int v  = p * 32 + (t >> 4);
            const int ng = t & 15;
            bf16x4 pk;
            pk[0] = (__bf16)vp[p].x;
            pk[1] = (__bf16)vp[p].y;
            pk[2] = (__bf16)vp[p].z;
            pk[3] = (__bf16)vp[p].w;
            *(bf16x4*)&Vbuf[v * 64 + ((ng >> 1) ^ (v & 7)) * 8 + 4 * (ng & 1)] = pk;
        }
        __syncthreads();   // B1

        // ---- prefetch it+1 (lands at next iter's stores; hidden behind GEMM1+GEMM2)
        const int n0n = n_base + ((it + 1) & 7) * 64;
        #pragma unroll
        for (int r = 0; r < 2; ++r)
            #pragma unroll
            for (int j = 0; j < 8; ++j)
                qp[r * 8 + j] = Qb[(size_t)(64 * r + 8 * w + j) * NT + n0n + l];
        #pragma unroll
        for (int p = 0; p < 4; ++p)
            vp[p] = *(const float4*)(Vb + (size_t)(p * 32 + (t >> 4)) * NT + n0n + 4 * (t & 15));

        // ---- GEMM1: S[n=32wn+..][m=32wm+..]
        f32x16 sacc;
        #pragma unroll
        for (int r = 0; r < 16; ++r) sacc[r] = 0.0f;
        const int nrow = 32 * wn + l31;
        #pragma unroll
        for (int k = 0; k < 8; ++k) {
            const bf16x8 af =
                *(const bf16x8*)&Qs[nrow * 128 + ((2 * k + lq) ^ (nrow & 15)) * 8];
            sacc = __builtin_amdgcn_mfma_f32_32x32x16_bf16(af, kf[k], sacc, 0, 0, 0);
        }

        // ---- sigmoid(x/sqrt(128)) -> Ss [m][n]
        #pragma unroll
        for (int g = 0; g < 4; ++g) {
            bf16x4 pk;
            #pragma unroll
            for (int rr = 0; rr < 4; ++rr) {
                const float x = sacc[4 * g + rr];
                const float e = __expf(x * -0.08838834764831845f);
                pk[rr] = (__bf16)__builtin_amdgcn_rcpf(1.0f + e);
            }
            *(bf16x4*)&Ss[mrow * 64 + ((4 * wn + g) ^ (mrow & 7)) * 8 + 4 * lq] = pk;
        }
        __syncthreads();   // B2

        // ---- GEMM2: oacc += V * S   (no end barrier: Vs double-buffered,
        //      Qs next-write is post-B2, Ss next-write is post-next-B1)
        #pragma unroll
        for (int k = 0; k < 4; ++k) {
            const int sw = 2 * k + lq;
            const bf16x8 av0 =
                *(const bf16x8*)&Vbuf[(64 * wn + l31) * 64 + (sw ^ (l31 & 7)) * 8];
            const bf16x8 av1 =
                *(const bf16x8*)&Vbuf[(64 * wn + 32 + l31) * 64 + (sw ^ (l31 & 7)) * 8];
            const bf16x8 bs =
                *(const bf16x8*)&Ss[mrow * 64 + (sw ^ (mrow & 7)) * 8];
            oacc[0] = __builtin_amdgcn_mfma_f32_32x32x16_bf16(av0, bs, oacc[0], 0, 0, 0);
            oacc[1] = __builtin_amdgcn_mfma_f32_32x32x16_bf16(av1, bs, oacc[1], 0, 0, 0);
        }
    }

    // ---- epilogue
    if (WSMODE == 0) {
        float* wsb = outp + (size_t)bid * 16384;   // partial [v 128][m 128]
        #pragma unroll
        for (int tv = 0; tv < 2; ++tv) {
            #pragma unroll
            for (int r = 0; r < 16; ++r) {
                const int v = 64 * wn + 32 * tv + (r & 3) + 8 * (r >> 2) + 4 * lq;
                wsb[v * 128 + mrow] = oacc[tv][r];
            }
        }
    } else {
        float* Ob = outp + (size_t)b * DT * NT;
        #pragma unroll
        for (int tv = 0; tv < 2; ++tv) {
            #pragma unroll
            for (int r = 0; r < 16; ++r) {
                const int v = 64 * wn + 32 * tv + (r & 3) + 8 * (r >> 2) + 4 * lq;
                atomicAdd(&Ob[(size_t)v * NT + m_blk + mrow], oacc[tv][r]);
            }
        }
    }
}

// out[o] = sum over 4 n-splits of ws partials; float4 per thread, fully coalesced
__global__ __launch_bounds__(256)
void reduce4(const float4* __restrict__ ws, float4* __restrict__ out)
{
    const int i = blockIdx.x * 256 + threadIdx.x;    // float4 index, 0..524287
    const int o = i * 4;
    const int m_glob = o & 2047;
    const int vb     = o >> 11;        // v + 128*b
    const int v      = vb & 127;
    const int bb     = vb >> 7;
    const int mt     = m_glob >> 7;
    const int m      = m_glob & 127;
    const size_t base = ((size_t)(bb + 8 * mt) * 16384 + (size_t)v * 128 + m) >> 2;
    const size_t strd = 524288;        // 128 blocks * 16384 floats / 4
    float4 a = ws[base];
    float4 c = ws[base + strd];
    float4 d = ws[base + 2 * strd];
    float4 e = ws[base + 3 * strd];
    float4 r;
    r.x = a.x + c.x + d.x + e.x;
    r.y = a.y + c.y + d.y + e.y;
    r.z = a.z + c.z + d.z + e.z;
    r.w = a.w + c.w + d.w + e.w;
    out[i] = r;
}

extern "C" void kernel_launch(void* const* d_in, const int* in_sizes, int n_in,
                              void* d_out, int out_size, void* d_ws, size_t ws_size,
                              hipStream_t stream) {
    (void)in_sizes; (void)n_in;
    const float* Q = (const float*)d_in[0];
    const float* K = (const float*)d_in[1];
    const float* V = (const float*)d_in[2];
    const size_t need = (size_t)512 * 16384 * 4;   // 33.5 MB of fp32 partials
    if (ws_size >= need) {
        sig_attn<0><<<dim3(512), dim3(512), 0, stream>>>(Q, K, V, (float*)d_ws);
        reduce4<<<dim3(2048), dim3(256), 0, stream>>>((const float4*)d_ws, (float4*)d_out);
    } else {
        // fallback: atomic merge into out (needs zeroed out; harness poisons with 0xAA)
        hipMemsetAsync(d_out, 0, (size_t)out_size * sizeof(float), stream);
        sig_attn<1><<<dim3(512), dim3(512), 0, stream>>>(Q, K, V, (float*)d_out);
    }
}